// Round 4
// baseline (376.042 us; speedup 1.0000x reference)
//
#include <hip/hip_runtime.h>
#include <math.h>

// Problem constants: B=64, MAX_H=64, MAX_W=32, D=512, S=8, HID=64
#define NB    64
#define MAXH  64
#define MAXW  32
#define DCH   512
#define SS    8
#define HID   64

#define QTOTAL ((size_t)NB * MAXH * MAXW * DCH)   // 67,108,864 floats

typedef float f4 __attribute__((ext_vector_type(4)));

__device__ __forceinline__ float gelu_exact(float x) {
    // jax.nn.gelu(approximate=False): x * 0.5 * (1 + erf(x/sqrt(2)))
    return 0.5f * x * (1.0f + erff(x * 0.70710678118654752440f));
}

// ---------------------------------------------------------------------------
// Kernel 1: precompute h[b][i][j][k] = gelu(u*w1[0][k] + v*w1[1][k] + b1[k])
// into d_ws, laid out for wave-uniform scalar loads by kernel 2:
//   flat f4 index T = ((blk*2 + jg)*16 + kq)*16 + s,  j = jg + 2s, k = 4kq+q
// Total 2^21 f4 = 33.5 MB.
// ---------------------------------------------------------------------------
__global__ __launch_bounds__(256) void hprep_kernel(
    const float* __restrict__ w1,     // (2,64)
    const float* __restrict__ b1,     // (64,)
    const int*   __restrict__ hlist,  // (64,)
    const int*   __restrict__ wlist,  // (64,)
    float* __restrict__ hg)           // (2^21 f4) in d_ws
{
    const int T   = blockIdx.x * 256 + threadIdx.x;  // 0 .. 2^21-1
    const int s   = T & 15;
    const int kq  = (T >> 4) & 15;
    const int jg  = (T >> 8) & 1;
    const int blk = T >> 9;           // b*64 + i
    const int b   = blk >> 6;
    const int i   = blk & 63;

    int H = hlist[b]; H = min(max(H, 1), MAXH);
    int W = wlist[b]; W = min(max(W, 1), MAXW);

    const float u    = (H > 1) ? (float)i / (float)(H - 1) : 0.0f;
    const float winv = (W > 1) ? 1.0f / (float)(W - 1) : 0.0f;
    const int   j    = jg + 2 * s;
    const float v    = (float)j * winv;

    const f4 w1a = ((const f4*)w1)[kq];          // w1[0][4kq..]
    const f4 w1b = ((const f4*)(w1 + HID))[kq];  // w1[1][4kq..]
    const f4 b1v = ((const f4*)b1)[kq];

    const f4 x = u * w1a + v * w1b + b1v;
    f4 h;
    h.x = gelu_exact(x.x);
    h.y = gelu_exact(x.y);
    h.z = gelu_exact(x.z);
    h.w = gelu_exact(x.w);
    ((f4*)hg)[T] = h;
}

// ---------------------------------------------------------------------------
// Kernel 2: per (b,i) row — bilinear from LDS-staged y-lerp + GEMV with h
// coming in through the SCALAR pipe (wave-uniform address -> s_load), so the
// LDS pipe only carries the 32 bilinear reads, not the 256 GEMV broadcasts.
// ---------------------------------------------------------------------------
__global__ __launch_bounds__(256) void hgqg_kernel(
    const float* __restrict__ canonical,  // (8,8,512)
    const float* __restrict__ w2,         // (64,512)
    const float* __restrict__ b2,         // (512,)
    const int*   __restrict__ hlist,      // (64,)
    const int*   __restrict__ wlist,      // (64,)
    const float* __restrict__ hg,         // precomputed h in d_ws
    float* __restrict__ out)              // queries flat, then mask flat
{
    const int blk = blockIdx.x;       // b*64 + i
    const int b   = blk >> 6;
    const int i   = blk & 63;
    const int t   = threadIdx.x;

    int H = hlist[b]; H = min(max(H, 1), MAXH);
    int W = wlist[b]; W = min(max(W, 1), MAXW);

    f4* q4 = (f4*)(out + (size_t)blk * (MAXW * DCH));

    // mask row: bool -> 0.0/1.0 floats
    if (t < MAXW) {
        out[QTOTAL + (size_t)blk * MAXW + t] = (i < H && t < W) ? 1.0f : 0.0f;
    }

    const f4 z = {0.f, 0.f, 0.f, 0.f};

    if (i >= H) {
        #pragma unroll
        for (int r = 0; r < 16; ++r) q4[t + r * 256] = z;
        return;
    }

    // ---- per-row uniforms ----
    const float u    = (H > 1) ? (float)i / (float)(H - 1) : 0.0f;
    const float sy   = fminf(u * 7.0f, 7.0f);
    const int   y0   = (int)sy;
    const int   y1   = min(y0 + 1, SS - 1);
    const float wy   = sy - (float)y0;
    const float winv = (W > 1) ? 1.0f / (float)(W - 1) : 0.0f;

    // ---- stage A: y-lerped canonical rows -> LDS (16 KB) ----
    __shared__ f4 ri[SS * 128];
    {
        const f4* can4 = (const f4*)canonical;
        #pragma unroll
        for (int r = 0; r < 4; ++r) {
            const int idx = t + r * 256;       // 0..1023
            const int x   = idx >> 7;
            const int c   = idx & 127;
            const f4 a = can4[(y0 * SS + x) * 128 + c];
            const f4 d = can4[(y1 * SS + x) * 128 + c];
            ri[idx] = a + wy * (d - a);
        }
    }
    __syncthreads();

    // ---- main: thread owns 4 channels (cid) for 16 interleaved j's ----
    const int cid = t & 127;                                  // 0..127
    const int jg  = __builtin_amdgcn_readfirstlane(t >> 7);   // 0 or 1, SGPR
    const f4  bb2 = ((const f4*)b2)[cid];

    f4 acc[16];

    // init: bilinear (x-lerp of y-lerped LDS rows) + b2, branchless
    #pragma unroll
    for (int s = 0; s < 16; ++s) {
        const int   j  = jg + 2 * s;
        const float v  = (float)j * winv;
        const float sx = fminf(v * 7.0f, 7.0f);
        const int   x0 = (int)sx;
        const int   x1 = min(x0 + 1, SS - 1);
        const float wx = sx - (float)x0;
        const f4 f0 = ri[x0 * 128 + cid];
        const f4 f1 = ri[x1 * 128 + cid];
        acc[s] = f0 + wx * (f1 - f0) + bb2;
    }

    // GEMV: acc[s] += sum_k h[j][k] * w2[k][4c..]
    // h comes from global, wave-uniform address -> scalar loads (SMEM pipe),
    // SGPR multipliers; w2 register-double-buffered vector loads.
    const f4* hb0 = (const f4*)hg + (((size_t)blk * 2 + jg) << 8);  // *256 f4
    const f4* wp  = (const f4*)w2 + cid;

    f4 wa = wp[0 * 128], wb = wp[1 * 128], wc = wp[2 * 128], wd = wp[3 * 128];
    #pragma unroll 1
    for (int kq = 0; kq < 16; ++kq) {
        const int kn = (kq < 15) ? (4 * kq + 4) : (4 * kq);  // next k base
        const f4 na = wp[(kn + 0) * 128];
        const f4 nb = wp[(kn + 1) * 128];
        const f4 nc = wp[(kn + 2) * 128];
        const f4 nd = wp[(kn + 3) * 128];
        const f4* hb = hb0 + (kq << 4);       // 16 f4, one per s — uniform
        #pragma unroll
        for (int s = 0; s < 16; ++s) {
            const f4 h4 = hb[s];              // s_load_dwordx4 -> SGPRs
            acc[s] += h4.x * wa + h4.y * wb + h4.z * wc + h4.w * wd;
        }
        wa = na; wb = nb; wc = nc; wd = nd;
    }

    // store (mask j >= W to zero)
    #pragma unroll
    for (int s = 0; s < 16; ++s) {
        const int j = jg + 2 * s;
        q4[j * 128 + cid] = (j < W) ? acc[s] : z;
    }
}

extern "C" void kernel_launch(void* const* d_in, const int* in_sizes, int n_in,
                              void* d_out, int out_size, void* d_ws, size_t ws_size,
                              hipStream_t stream) {
    const float* canonical = (const float*)d_in[0];
    const float* w1        = (const float*)d_in[1];
    const float* b1        = (const float*)d_in[2];
    const float* w2        = (const float*)d_in[3];
    const float* b2        = (const float*)d_in[4];
    const int*   hlist     = (const int*)d_in[6];
    const int*   wlist     = (const int*)d_in[7];
    float* out = (float*)d_out;
    float* hg  = (float*)d_ws;   // 33.5 MB of h values

    // 2^21 f4 outputs, 256 threads each doing one f4 -> 8192 blocks
    hprep_kernel<<<8192, 256, 0, stream>>>(w1, b1, hlist, wlist, hg);
    hgqg_kernel<<<NB * MAXH, 256, 0, stream>>>(
        canonical, w2, b2, hlist, wlist, hg, out);
}

// Round 5
// 306.937 us; speedup vs baseline: 1.2251x; 1.2251x over previous
//
#include <hip/hip_runtime.h>
#include <math.h>

// Problem constants: B=64, MAX_H=64, MAX_W=32, D=512, S=8, HID=64
#define NB    64
#define MAXH  64
#define MAXW  32
#define DCH   512
#define SS    8
#define HID   64

#define QTOTAL ((size_t)NB * MAXH * MAXW * DCH)   // 67,108,864 floats

typedef float f4 __attribute__((ext_vector_type(4)));

__device__ __forceinline__ float gelu_exact(float x) {
    // jax.nn.gelu(approximate=False): x * 0.5 * (1 + erf(x/sqrt(2)))
    return 0.5f * x * (1.0f + erff(x * 0.70710678118654752440f));
}

// One block = one (b, i, half): 16 j's x 512 channels = 32 KB of output.
// Grid 8192. Block index is swizzled so each CU's resident set spans many
// (b, i) values — the natural mapping gives every CU a FIXED i (blk mod 64
// is invariant under blk += 256), serializing all GEMV work onto low-i CUs.
__global__ __launch_bounds__(256) void hgqg_kernel(
    const float* __restrict__ canonical,  // (8,8,512)
    const float* __restrict__ w1,         // (2,64)
    const float* __restrict__ b1,         // (64,)
    const float* __restrict__ w2,         // (64,512)
    const float* __restrict__ b2,         // (512,)
    const int*   __restrict__ hlist,      // (64,)
    const int*   __restrict__ wlist,      // (64,)
    float* __restrict__ out)              // queries flat, then mask flat
{
    // ---- bijective swizzle: id = raw ^ (raw>>7) on 13 bits ----
    const int raw  = blockIdx.x;                 // 0..8191
    const int id   = (raw ^ (raw >> 7)) & 8191;
    const int i    = id & 63;
    const int half = (id >> 6) & 1;
    const int b    = id >> 7;                    // 0..63
    const int blk  = (b << 6) | i;               // output row index
    const int t    = threadIdx.x;

    int H = hlist[b]; H = min(max(H, 1), MAXH);
    int W = wlist[b]; W = min(max(W, 1), MAXW);

    const int jbase = half << 4;                 // 0 or 16

    // this block's 32 KB output region: j in [jbase, jbase+16)
    f4* q4 = (f4*)(out + (size_t)blk * (MAXW * DCH)) + jbase * 128;

    // mask row (half 0 only): bool -> 0.0/1.0 floats
    if (half == 0 && t < MAXW) {
        out[QTOTAL + (size_t)blk * MAXW + t] = (i < H && t < W) ? 1.0f : 0.0f;
    }

    const f4 z = {0.f, 0.f, 0.f, 0.f};

    if (i >= H || jbase >= W) {
        // all 16 j's masked: 16*512 floats = 2048 f4 of zeros
        #pragma unroll
        for (int r = 0; r < 8; ++r) q4[t + r * 256] = z;
        return;
    }

    // ---- per-row uniforms ----
    const float u    = (H > 1) ? (float)i / (float)(H - 1) : 0.0f;
    const float sy   = fminf(u * 7.0f, 7.0f);
    const int   y0   = (int)sy;
    const int   y1   = min(y0 + 1, SS - 1);
    const float wy   = sy - (float)y0;
    const float winv = (W > 1) ? 1.0f / (float)(W - 1) : 0.0f;

    // ---- hsh[jl][k] = gelu(u*w1[0][k] + v*w1[1][k] + b1[k]), jl = j-jbase ----
    __shared__ __align__(16) float hsh[16][HID];   // 4 KB
    {
        const int jl = t >> 4;              // 0..15
        const int k0 = (t & 15) * 4;        // 0..60
        const float v = (float)(jbase + jl) * winv;
        #pragma unroll
        for (int kk = 0; kk < 4; ++kk) {
            const int k = k0 + kk;
            hsh[jl][k] = gelu_exact(u * w1[k] + v * w1[HID + k] + b1[k]);
        }
    }
    __syncthreads();

    // ---- main: thread owns 4 channels (cid) for 8 interleaved j's ----
    const int cid = t & 127;          // channel/4 index 0..127
    const int jg  = t >> 7;           // 0 or 1; j = jbase + jg + 2s
    const f4  bb2 = ((const f4*)b2)[cid];
    const f4* can4 = (const f4*)canonical;
    const f4* wp   = (const f4*)w2 + cid;

    f4 acc[8];
    #pragma unroll
    for (int s = 0; s < 8; ++s) acc[s] = z;

    if (jbase + jg < W) {   // wave-uniform: any active j for this wave?
        // init: bilinear + b2 (guarded per s)
        #pragma unroll
        for (int s = 0; s < 8; ++s) {
            const int j = jbase + jg + 2 * s;
            if (j < W) {
                const float v  = (float)j * winv;
                const float sx = fminf(v * 7.0f, 7.0f);
                const int   x0 = (int)sx;
                const int   x1 = min(x0 + 1, SS - 1);
                const float wx = sx - (float)x0;
                const f4 q00 = can4[(y0 * SS + x0) * 128 + cid];
                const f4 q01 = can4[(y0 * SS + x1) * 128 + cid];
                const f4 q10 = can4[(y1 * SS + x0) * 128 + cid];
                const f4 q11 = can4[(y1 * SS + x1) * 128 + cid];
                const f4 t0 = q00 + wx * (q01 - q00);
                const f4 t1 = q10 + wx * (q11 - q10);
                acc[s] = t0 + wy * (t1 - t0) + bb2;
            }
        }
        // GEMV: acc[s] += sum_k h[j][k] * w2[k][4c..]
        #pragma unroll 1
        for (int kb = 0; kb < HID; kb += 4) {
            const f4 wa = wp[(kb + 0) * 128];
            const f4 wb = wp[(kb + 1) * 128];
            const f4 wc = wp[(kb + 2) * 128];
            const f4 wd = wp[(kb + 3) * 128];
            #pragma unroll
            for (int s = 0; s < 8; ++s) {
                const int j = jbase + jg + 2 * s;
                if (j < W) {
                    const int jl = jg + 2 * s;
                    const f4 h4 = *(const f4*)&hsh[jl][kb];  // uniform -> broadcast
                    acc[s] += h4.x * wa + h4.y * wb + h4.z * wc + h4.w * wd;
                }
            }
        }
    }

    // store (acc already zero for masked j)
    #pragma unroll
    for (int s = 0; s < 8; ++s) {
        const int j = jg + 2 * s;          // local j within the half
        q4[j * 128 + cid] = acc[s];
    }
}

extern "C" void kernel_launch(void* const* d_in, const int* in_sizes, int n_in,
                              void* d_out, int out_size, void* d_ws, size_t ws_size,
                              hipStream_t stream) {
    const float* canonical = (const float*)d_in[0];
    const float* w1        = (const float*)d_in[1];
    const float* b1        = (const float*)d_in[2];
    const float* w2        = (const float*)d_in[3];
    const float* b2        = (const float*)d_in[4];
    const int*   hlist     = (const int*)d_in[6];
    const int*   wlist     = (const int*)d_in[7];
    float* out = (float*)d_out;

    hgqg_kernel<<<2 * NB * MAXH, 256, 0, stream>>>(
        canonical, w1, b1, w2, b2, hlist, wlist, out);
}

// Round 6
// 280.890 us; speedup vs baseline: 1.3388x; 1.0927x over previous
//
#include <hip/hip_runtime.h>
#include <math.h>

// Problem constants: B=64, MAX_H=64, MAX_W=32, D=512, S=8, HID=64
#define NB    64
#define MAXH  64
#define MAXW  32
#define DCH   512
#define SS    8
#define HID   64

#define QTOTAL ((size_t)NB * MAXH * MAXW * DCH)   // 67,108,864 floats

typedef float f4  __attribute__((ext_vector_type(4)));
typedef short s8v __attribute__((ext_vector_type(8)));   // 8 bf16 (4 VGPRs)

__device__ __forceinline__ float gelu_exact(float x) {
    // jax.nn.gelu(approximate=False): x * 0.5 * (1 + erf(x/sqrt(2)))
    return 0.5f * x * (1.0f + erff(x * 0.70710678118654752440f));
}

__device__ __forceinline__ unsigned short bf16_rne(float x) {
    unsigned int u = __float_as_uint(x);
    unsigned int r = u + 0x7fffu + ((u >> 16) & 1u);
    return (unsigned short)(r >> 16);
}

// ---------------------------------------------------------------------------
// Prep: w2 (64x512 f32) -> bf16 table in MFMA B-fragment order (64 KB, d_ws).
// For 16x16x32 bf16 MFMA, lane l of a wave holds B[k=(l>>4)*8+j][n=l&15],
// j=0..7. Table entry (kh, ct, lane) packs those 8 bf16:
//   k = 32*kh + (l>>4)*8 + j,  c = 16*ct + (l&15)
// Flat index = (kh*32 + ct)*64 + lane  (== tid below).
// ---------------------------------------------------------------------------
__global__ __launch_bounds__(256) void w2prep_kernel(
    const float* __restrict__ w2, s8v* __restrict__ w2b)
{
    const int tid  = blockIdx.x * 256 + threadIdx.x;   // 0..4095
    const int lane = tid & 63;
    const int ct   = (tid >> 6) & 31;
    const int kh   = tid >> 11;                        // 0..1
    const int q    = lane >> 4;
    const int m    = lane & 15;
    const int c    = ct * 16 + m;
    union { s8v v; unsigned short us[8]; } pk;
    #pragma unroll
    for (int j = 0; j < 8; ++j) {
        const int k = kh * 32 + q * 8 + j;
        pk.us[j] = bf16_rne(w2[k * DCH + c]);
    }
    w2b[tid] = pk.v;
}

// ---------------------------------------------------------------------------
// Main: one block = (b, i, half) -> 16 j x 512 c. 4 waves, each wave owns
// 128 channels = 8 MFMA tiles. delta via mfma_f32_16x16x32_bf16 (2 K-halves),
// bilinear+b2 seeded into the C fragment, mask applied at store.
// ---------------------------------------------------------------------------
__global__ __launch_bounds__(256) void hgqg_kernel(
    const float* __restrict__ canonical,  // (8,8,512)
    const float* __restrict__ w1,         // (2,64)
    const float* __restrict__ b1,         // (64,)
    const s8v*   __restrict__ w2b,        // B-frag bf16 table (d_ws)
    const float* __restrict__ b2,         // (512,)
    const int*   __restrict__ hlist,      // (64,)
    const int*   __restrict__ wlist,      // (64,)
    float* __restrict__ out)              // queries flat, then mask flat
{
    // bijective swizzle (R5): spreads (b,i) across CUs
    const int raw  = blockIdx.x;                 // 0..8191
    const int id   = (raw ^ (raw >> 7)) & 8191;
    const int i    = id & 63;
    const int half = (id >> 6) & 1;
    const int b    = id >> 7;
    const int blk  = (b << 6) | i;
    const int t    = threadIdx.x;

    int H = hlist[b]; H = min(max(H, 1), MAXH);
    int W = wlist[b]; W = min(max(W, 1), MAXW);

    const int jbase = half << 4;                 // 0 or 16

    f4* q4 = (f4*)(out + (size_t)blk * (MAXW * DCH)) + jbase * 128;

    if (half == 0 && t < MAXW) {
        out[QTOTAL + (size_t)blk * MAXW + t] = (i < H && t < W) ? 1.0f : 0.0f;
    }

    const f4 z = {0.f, 0.f, 0.f, 0.f};

    if (i >= H || jbase >= W) {
        #pragma unroll
        for (int r = 0; r < 8; ++r) q4[t + r * 256] = z;
        return;
    }

    // ---- per-row uniforms ----
    const float u    = (H > 1) ? (float)i / (float)(H - 1) : 0.0f;
    const float sy   = fminf(u * 7.0f, 7.0f);
    const int   y0   = (int)sy;
    const int   y1   = min(y0 + 1, SS - 1);
    const float wy   = sy - (float)y0;
    const float winv = (W > 1) ? 1.0f / (float)(W - 1) : 0.0f;

    // ---- stage A: y-lerped canonical rows -> LDS, padded stride 516 ----
    __shared__ __align__(16) float ri[SS * 516];     // 16.5 KB
    {
        const f4* can4 = (const f4*)canonical;
        #pragma unroll
        for (int rr = 0; rr < 4; ++rr) {
            const int idx = t + rr * 256;     // 0..1023
            const int x   = idx >> 7;
            const int c4  = idx & 127;
            const f4 a = can4[(y0 * SS + x) * 128 + c4];
            const f4 d = can4[(y1 * SS + x) * 128 + c4];
            *(f4*)&ri[x * 516 + c4 * 4] = a + wy * (d - a);
        }
    }

    // ---- stage B: hsh[jl][k] = gelu(u*w1[0][k] + v*w1[1][k] + b1[k]) ----
    __shared__ __align__(16) float hsh[16][68];      // padded: bank spread
    {
        const int jl = t >> 4;              // 0..15
        const int k0 = (t & 15) * 4;        // 0..60
        const float v = (float)(jbase + jl) * winv;
        #pragma unroll
        for (int kk = 0; kk < 4; ++kk) {
            const int k = k0 + kk;
            hsh[jl][k] = gelu_exact(u * w1[k] + v * w1[HID + k] + b1[k]);
        }
    }
    __syncthreads();

    // ---- wave decomposition ----
    const int l = t & 63;          // lane
    const int w = t >> 6;          // wave 0..3 -> channels [w*128, w*128+128)
    const int q = l >> 4;          // quad
    const int m = l & 15;          // lane-in-quad

    // A-fragments: lane holds A[m][k=q*8+j]; A = h[j_local][k]
    union { s8v v; unsigned short us[8]; } A0, A1;
    {
        const float* hrow = &hsh[m][q * 8];
        #pragma unroll
        for (int j = 0; j < 8; ++j) {
            A0.us[j] = bf16_rne(hrow[j]);
            A1.us[j] = bf16_rne(hrow[32 + j]);
        }
    }

    // per-reg bilinear x-weights: C/D row = q*4 + r  ->  j = jbase + q*4 + r
    int   x0a[4], x1a[4];
    float wxa[4];
    #pragma unroll
    for (int r = 0; r < 4; ++r) {
        const int   j  = jbase + q * 4 + r;
        const float v  = (float)j * winv;
        const float sx = fminf(v * 7.0f, 7.0f);
        const int   x0 = (int)sx;
        x0a[r] = x0;
        x1a[r] = min(x0 + 1, SS - 1);
        wxa[r] = sx - (float)x0;
    }

    const size_t obase = (size_t)blk * (MAXW * DCH) + (size_t)jbase * DCH;

    #pragma unroll
    for (int tt = 0; tt < 8; ++tt) {
        const int ct = w * 8 + tt;           // c-tile 0..31
        const int c  = ct * 16 + m;          // this lane's channel (C/D col)

        // seed C with bilinear + b2 (C layout: row = q*4+r, col = m)
        f4 acc;
        const float bb2 = b2[c];
        #pragma unroll
        for (int r = 0; r < 4; ++r) {
            const float f0 = ri[x0a[r] * 516 + c];
            const float f1 = ri[x1a[r] * 516 + c];
            acc[r] = f0 + wxa[r] * (f1 - f0) + bb2;
        }

        // delta: two chained K=32 MFMAs
        const s8v b0 = w2b[ct * 64 + l];            // kh=0
        const s8v b1f = w2b[2048 + ct * 64 + l];    // kh=1
        acc = __builtin_amdgcn_mfma_f32_16x16x32_bf16(A0.v, b0, acc, 0, 0, 0);
        acc = __builtin_amdgcn_mfma_f32_16x16x32_bf16(A1.v, b1f, acc, 0, 0, 0);

        // store with mask (j >= W -> 0); 16 lanes/quad = 64 B contiguous
        #pragma unroll
        for (int r = 0; r < 4; ++r) {
            const int j = jbase + q * 4 + r;
            out[obase + (size_t)(q * 4 + r) * DCH + c] = (j < W) ? acc[r] : 0.0f;
        }
    }
}

extern "C" void kernel_launch(void* const* d_in, const int* in_sizes, int n_in,
                              void* d_out, int out_size, void* d_ws, size_t ws_size,
                              hipStream_t stream) {
    const float* canonical = (const float*)d_in[0];
    const float* w1        = (const float*)d_in[1];
    const float* b1        = (const float*)d_in[2];
    const float* w2        = (const float*)d_in[3];
    const float* b2        = (const float*)d_in[4];
    const int*   hlist     = (const int*)d_in[6];
    const int*   wlist     = (const int*)d_in[7];
    float* out = (float*)d_out;
    s8v*   w2b = (s8v*)d_ws;   // 64 KB bf16 B-fragment table

    w2prep_kernel<<<16, 256, 0, stream>>>(w2, w2b);
    hgqg_kernel<<<2 * NB * MAXH, 256, 0, stream>>>(
        canonical, w1, b1, w2b, b2, hlist, wlist, out);
}